// Round 1
// baseline (2738.217 us; speedup 1.0000x reference)
//
#include <hip/hip_runtime.h>

#define ALPHA 0.2f
#define NT 1000       // n types == index range of src AND dst
#define NRELC 200
#define NE 500000
#define N_ENT 100000

// ---------------- workspace layout (float offsets) ----------------
static constexpr size_t S1       = 1195000;   // per layer-1 combo
static constexpr size_t OFF_P1   = 0;         // 1000x64 entity proj
static constexpr size_t OFF_P2   = 64000;     // 1000x64 type proj
static constexpr size_t OFF_C1   = 128000;    // 1000 score coeff (src)
static constexpr size_t OFF_C2   = 129000;    // 1000 score coeff (dst)
static constexpr size_t OFF_DEN  = 130000;    // 1000
static constexpr size_t OFF_ACCE = 131000;    // 1000x64  sum s*e
static constexpr size_t OFF_T    = 195000;    // 1000x1000 sum s by (seg,other)

static constexpr size_t OFF_U1   = 4*S1;              // 4*3*64 u-vectors L1
static constexpr size_t OFF_U2   = OFF_U1 + 768;      // 2*3*128 u-vectors L2
static constexpr size_t OFF_X1   = OFF_U2 + 768;      // 1000x128 concat entity feats
static constexpr size_t OFF_X2   = OFF_X1 + 128000;   // 1000x128 concat type feats
static constexpr size_t OFF_OR   = OFF_X2 + 128000;   // 200x128 out_rel
static constexpr size_t OFF_L2   = OFF_OR + 25600;

static constexpr size_t S2     = 1484800;     // per layer-2 combo
static constexpr size_t L2_Q1  = 0;           // 1000x128
static constexpr size_t L2_Q2  = 128000;      // 1000x128
static constexpr size_t L2_R3  = 256000;      // 200x128 out_rel @ a3^T
static constexpr size_t L2_C1  = 281600;      // 1000
static constexpr size_t L2_C2  = 282600;      // 1000
static constexpr size_t L2_C3  = 283600;      // 200
static constexpr size_t L2_DEN = 283800;      // 1000
static constexpr size_t L2_U   = 284800;      // 1000x200
static constexpr size_t L2_T   = 484800;      // 1000x1000

static constexpr size_t WS_FLOATS = OFF_L2 + 2*S2;    // ~8.03M floats = 32.1MB

// ---------------- output layout (floats) ----------------
static constexpr size_t OUT_O2  = 12800000;   // 100000*128
static constexpr size_t OUT_REL = 12928000;   // + 1000*128

__device__ __forceinline__ float eluf(float x) { return x > 0.f ? x : expm1f(x); }
__device__ __forceinline__ float scoref(float slin) {
  // exp(-leaky_relu(slin, 0.2))
  return expf(slin > 0.f ? -slin : -ALPHA * slin);
}

// ---- u[c][p] = a_part_p^T @ v  (score factorization vectors) ----
__global__ void k_prep_u(const float* aE0, const float* vE0, const float* aT0, const float* vT0,
                         const float* aE1, const float* vE1, const float* aT1, const float* vT1,
                         const float* aEo, const float* vEo, const float* aTo, const float* vTo,
                         float* ws) {
  int t = blockIdx.x * blockDim.x + threadIdx.x;
  if (t < 768) {                       // layer 1: 4 combos x 3 parts x 64
    int c = t / 192, rem = t - c*192;
    int p = rem >> 6, k = rem & 63;
    const float* a = (c==0)?aE0:(c==1)?aT0:(c==2)?aE1:aT1;
    const float* v = (c==0)?vE0:(c==1)?vT0:(c==2)?vE1:vT1;
    float s = 0.f;
    for (int o = 0; o < 64; ++o) s += a[o*192 + p*64 + k] * v[o];
    ws[OFF_U1 + (size_t)(c*3+p)*64 + k] = s;
  } else if (t < 1536) {               // layer 2: 2 combos x 3 parts x 128
    int tt = t - 768;
    int c = tt / 384, rem = tt - c*384;
    int p = rem >> 7, k = rem & 127;
    const float* a = c ? aTo : aEo;
    const float* v = c ? vTo : vEo;
    float s = 0.f;
    for (int o = 0; o < 128; ++o) s += a[o*384 + p*128 + k] * v[o];
    ws[OFF_U2 + (size_t)(c*3+p)*128 + k] = s;
  }
}

// ---- layer-1 projections P1,P2 (1000x64 each) and score coeffs c1,c2 ----
__global__ void k_l1_proj(const float* Ent, const float* Typ,
                          const float* aE0, const float* aT0,
                          const float* aE1, const float* aT1,
                          float* ws) {
  int stride = gridDim.x * blockDim.x;
  for (int t = blockIdx.x * blockDim.x + threadIdx.x; t < 4*130000; t += stride) {
    int c = t / 130000, rem = t - c*130000;
    const float* a = (c==0)?aE0:(c==1)?aT0:(c==2)?aE1:aT1;
    float* base = ws + (size_t)c * S1;
    if (rem < 64000) {                       // P1[i][o] = Ent[i] . a1[o]
      int i = rem >> 6, o = rem & 63;
      const float* x = Ent + (size_t)i*64;
      const float* ar = a + o*192;
      float s = 0.f;
      #pragma unroll
      for (int k = 0; k < 64; ++k) s += x[k]*ar[k];
      base[OFF_P1 + rem] = s;
    } else if (rem < 128000) {               // P2[i][o] = Typ[i] . a2[o]
      int rr = rem - 64000; int i = rr >> 6, o = rr & 63;
      const float* x = Typ + (size_t)i*64;
      const float* ar = a + o*192 + 64;
      float s = 0.f;
      #pragma unroll
      for (int k = 0; k < 64; ++k) s += x[k]*ar[k];
      base[OFF_P2 + rr] = s;
    } else if (rem < 129000) {               // c1[i] = Ent[i] . u1
      int i = rem - 128000;
      const float* x = Ent + (size_t)i*64;
      const float* u = ws + OFF_U1 + (size_t)(c*3)*64;
      float s = 0.f;
      #pragma unroll
      for (int k = 0; k < 64; ++k) s += x[k]*u[k];
      base[OFF_C1 + i] = s;
    } else {                                 // c2[i] = Typ[i] . u2
      int i = rem - 129000;
      const float* x = Typ + (size_t)i*64;
      const float* u = ws + OFF_U1 + (size_t)(c*3+1)*64;
      float s = 0.f;
      #pragma unroll
      for (int k = 0; k < 64; ++k) s += x[k]*u[k];
      base[OFF_C2 + i] = s;
    }
  }
}

// ---- layer-1 edge pass: 16 lanes per edge, float4 per lane ----
__global__ __launch_bounds__(256) void k_l1_edge(const float* __restrict__ Eemb,
                                                 const int* __restrict__ srcA,
                                                 const int* __restrict__ dstA,
                                                 float* __restrict__ ws) {
  int t = blockIdx.x * blockDim.x + threadIdx.x;
  int j = t >> 4;
  int sub = t & 15;
  if (j >= NE) return;
  int s = srcA[j], d = dstA[j];
  const float4 ev = reinterpret_cast<const float4*>(Eemb)[t];   // t == j*16+sub
  #pragma unroll
  for (int c = 0; c < 4; ++c) {
    const float4 w = reinterpret_cast<const float4*>(ws + OFF_U1 + (size_t)(c*3+2)*64)[sub];
    float r = ev.x*w.x + ev.y*w.y + ev.z*w.z + ev.w*w.w;
    r += __shfl_xor(r, 1, 16);
    r += __shfl_xor(r, 2, 16);
    r += __shfl_xor(r, 4, 16);
    r += __shfl_xor(r, 8, 16);
    float* base = ws + (size_t)c * S1;
    float slin = base[OFF_C1 + s] + base[OFF_C2 + d] + r;
    float sv = scoref(slin);
    int z = c & 1;
    int seg = z ? d : s;
    int oth = z ? s : d;
    float* accE = base + OFF_ACCE + (size_t)seg*64 + sub*4;
    atomicAdd(accE + 0, sv*ev.x);
    atomicAdd(accE + 1, sv*ev.y);
    atomicAdd(accE + 2, sv*ev.z);
    atomicAdd(accE + 3, sv*ev.w);
    if (sub == 0) {
      atomicAdd(base + OFF_T + (size_t)seg*NT + oth, sv);
      atomicAdd(base + OFF_DEN + seg, sv);
    }
  }
}

// ---- layer-1 post: num = den*Pown + T@Poth + accE@a3^T ; write x1cat/x2cat ----
__global__ __launch_bounds__(256) void k_l1_post(const float* aE0, const float* aT0,
                                                 const float* aE1, const float* aT1,
                                                 float* ws) {
  __shared__ float Tl[NT];
  __shared__ float red[256];
  int bid = blockIdx.x;
  int c = bid / NT, g = bid - c*NT;
  const float* a = (c==0)?aE0:(c==1)?aT0:(c==2)?aE1:aT1;
  float* base = ws + (size_t)c * S1;
  for (int i = threadIdx.x; i < NT; i += 256)
    Tl[i] = base[OFF_T + (size_t)g*NT + i];
  __syncthreads();
  int o = threadIdx.x & 63;
  int part = threadIdx.x >> 6;          // 4 partial slices of d
  int z = c & 1;
  const float* Poth = base + (z ? OFF_P1 : OFF_P2);
  float sum = 0.f;
  for (int dd = part*250; dd < part*250 + 250; ++dd)
    sum += Tl[dd] * Poth[(size_t)dd*64 + o];
  red[threadIdx.x] = sum;
  __syncthreads();
  if (part == 0) {
    sum = red[o] + red[64+o] + red[128+o] + red[192+o];
    const float* accE = base + OFF_ACCE + (size_t)g*64;
    const float* a3 = a + o*192 + 128;
    float acc = 0.f;
    #pragma unroll
    for (int k = 0; k < 64; ++k) acc += accE[k]*a3[k];
    float den = base[OFF_DEN + g];
    float own = base[(z ? OFF_P2 : OFF_P1) + (size_t)g*64 + o];
    float num = sum + acc + den*own;
    float h = num / (den == 0.f ? 1.f : den);
    float outv = eluf(h);                 // concat=True -> elu
    float* dst = ws + (z ? OFF_X2 : OFF_X1);
    int hh = c >> 1;
    dst[(size_t)g*128 + hh*64 + o] = outv;
  }
}

// ---- out_rel = Rel @ W  (200x64 @ 64x128) ----
__global__ void k_relW(const float* Rel, const float* W, float* ws, float* dout) {
  int t = blockIdx.x * blockDim.x + threadIdx.x;
  if (t >= NRELC*128) return;
  int r = t >> 7, o = t & 127;
  const float* x = Rel + (size_t)r*64;
  float s = 0.f;
  #pragma unroll
  for (int k = 0; k < 64; ++k) s += x[k] * W[(size_t)k*128 + o];
  ws[OFF_OR + t] = s;
  dout[OUT_REL + t] = s;
}

// ---- layer-2 projections Q1,Q2,R3 and score coeffs ----
__global__ void k_l2_proj(const float* aEo, const float* aTo, float* ws) {
  int stride = gridDim.x * blockDim.x;
  const float* x1 = ws + OFF_X1;
  const float* x2 = ws + OFF_X2;
  const float* orel = ws + OFF_OR;
  for (int t = blockIdx.x * blockDim.x + threadIdx.x; t < 2*283800; t += stride) {
    int c = t / 283800, rem = t - c*283800;
    const float* a = c ? aTo : aEo;
    float* base = ws + OFF_L2 + (size_t)c * S2;
    if (rem < 128000) {
      int i = rem >> 7, o = rem & 127;
      const float* x = x1 + (size_t)i*128;
      const float* ar = a + (size_t)o*384;
      float s = 0.f;
      #pragma unroll
      for (int k = 0; k < 128; ++k) s += x[k]*ar[k];
      base[L2_Q1 + rem] = s;
    } else if (rem < 256000) {
      int rr = rem - 128000; int i = rr >> 7, o = rr & 127;
      const float* x = x2 + (size_t)i*128;
      const float* ar = a + (size_t)o*384 + 128;
      float s = 0.f;
      #pragma unroll
      for (int k = 0; k < 128; ++k) s += x[k]*ar[k];
      base[L2_Q2 + rr] = s;
    } else if (rem < 281600) {
      int rr = rem - 256000; int r = rr >> 7, o = rr & 127;
      const float* x = orel + (size_t)r*128;
      const float* ar = a + (size_t)o*384 + 256;
      float s = 0.f;
      #pragma unroll
      for (int k = 0; k < 128; ++k) s += x[k]*ar[k];
      base[L2_R3 + rr] = s;
    } else if (rem < 282600) {
      int i = rem - 281600;
      const float* u = ws + OFF_U2 + (size_t)(c*3)*128;
      const float* x = x1 + (size_t)i*128;
      float s = 0.f;
      for (int k = 0; k < 128; ++k) s += x[k]*u[k];
      base[L2_C1 + i] = s;
    } else if (rem < 283600) {
      int i = rem - 282600;
      const float* u = ws + OFF_U2 + (size_t)(c*3+1)*128;
      const float* x = x2 + (size_t)i*128;
      float s = 0.f;
      for (int k = 0; k < 128; ++k) s += x[k]*u[k];
      base[L2_C2 + i] = s;
    } else {
      int r = rem - 283600;
      const float* u = ws + OFF_U2 + (size_t)(c*3+2)*128;
      const float* x = orel + (size_t)r*128;
      float s = 0.f;
      for (int k = 0; k < 128; ++k) s += x[k]*u[k];
      base[L2_C3 + r] = s;
    }
  }
}

// ---- layer-2 edge pass: pure scalar scatter (6 atomics/edge) ----
__global__ void k_l2_edge(const int* __restrict__ srcA, const int* __restrict__ dstA,
                          const int* __restrict__ etA, float* __restrict__ ws) {
  int j = blockIdx.x * blockDim.x + threadIdx.x;
  if (j >= NE) return;
  int s = srcA[j], d = dstA[j], r = etA[j];
  #pragma unroll
  for (int c = 0; c < 2; ++c) {
    float* base = ws + OFF_L2 + (size_t)c * S2;
    float slin = base[L2_C1 + s] + base[L2_C2 + d] + base[L2_C3 + r];
    float sv = scoref(slin);
    int seg = c ? d : s;
    int oth = c ? s : d;
    atomicAdd(base + L2_T + (size_t)seg*NT + oth, sv);
    atomicAdd(base + L2_U + (size_t)seg*NRELC + r, sv);
    atomicAdd(base + L2_DEN + seg, sv);
  }
}

// ---- layer-2 post: num = den*Qown + T@Qoth + U@R3 ; write elu to d_out ----
__global__ __launch_bounds__(256) void k_l2_post(float* ws, float* dout) {
  __shared__ float Tl[NT];
  __shared__ float Ul[NRELC];
  __shared__ float red[256];
  int bid = blockIdx.x;
  int c = bid / NT, g = bid - c*NT;
  float* base = ws + OFF_L2 + (size_t)c * S2;
  for (int i = threadIdx.x; i < NT; i += 256)
    Tl[i] = base[L2_T + (size_t)g*NT + i];
  for (int i = threadIdx.x; i < NRELC; i += 256)
    Ul[i] = base[L2_U + (size_t)g*NRELC + i];
  __syncthreads();
  int o = threadIdx.x & 127;
  int part = threadIdx.x >> 7;          // 2 partial slices
  const float* Qoth = base + (c ? L2_Q1 : L2_Q2);
  const float* R3 = base + L2_R3;
  float sum = 0.f;
  for (int dd = part*500; dd < part*500 + 500; ++dd)
    sum += Tl[dd] * Qoth[(size_t)dd*128 + o];
  for (int rr = part*100; rr < part*100 + 100; ++rr)
    sum += Ul[rr] * R3[(size_t)rr*128 + o];
  red[threadIdx.x] = sum;
  __syncthreads();
  if (part == 0) {
    sum = red[o] + red[128+o];
    float den = base[L2_DEN + g];
    float own = base[(c ? L2_Q2 : L2_Q1) + (size_t)g*128 + o];
    float num = sum + den*own;
    float h = num / (den == 0.f ? 1.f : den);
    float outv = eluf(h);               // outer elu
    size_t off = c ? (OUT_O2 + (size_t)g*128 + o) : ((size_t)g*128 + o);
    dout[off] = outv;
  }
}

extern "C" void kernel_launch(void* const* d_in, const int* in_sizes, int n_in,
                              void* d_out, int out_size, void* d_ws, size_t ws_size,
                              hipStream_t stream) {
  (void)in_sizes; (void)n_in;
  const float* Ent = (const float*)d_in[0];
  const float* Typ = (const float*)d_in[1];
  const float* Rel = (const float*)d_in[2];
  const int*   edge = (const int*)d_in[3];
  const int*   etyp = (const int*)d_in[4];
  const float* Eemb = (const float*)d_in[5];
  const float* aE0 = (const float*)d_in[6];
  const float* vE0 = (const float*)d_in[7];
  const float* aT0 = (const float*)d_in[8];
  const float* vT0 = (const float*)d_in[9];
  const float* aE1 = (const float*)d_in[10];
  const float* vE1 = (const float*)d_in[11];
  const float* aT1 = (const float*)d_in[12];
  const float* vT1 = (const float*)d_in[13];
  const float* aEo = (const float*)d_in[14];
  const float* vEo = (const float*)d_in[15];
  const float* aTo = (const float*)d_in[16];
  const float* vTo = (const float*)d_in[17];
  const float* W   = (const float*)d_in[18];
  float* ws  = (float*)d_ws;
  float* out = (float*)d_out;
  const int* srcA = edge;
  const int* dstA = edge + NE;

  if (ws_size < WS_FLOATS * sizeof(float)) return;   // workspace too small -> fail loudly

  // zero output (o1 rows >= 1000 stay exactly 0 == elu(0)) and accumulators
  hipMemsetAsync(d_out, 0, (size_t)out_size * sizeof(float), stream);
  hipMemsetAsync(d_ws, 0, WS_FLOATS * sizeof(float), stream);

  k_prep_u<<<6, 256, 0, stream>>>(aE0,vE0,aT0,vT0,aE1,vE1,aT1,vT1,aEo,vEo,aTo,vTo,ws);
  k_l1_proj<<<2048, 256, 0, stream>>>(Ent, Typ, aE0, aT0, aE1, aT1, ws);
  k_l1_edge<<<31250, 256, 0, stream>>>(Eemb, srcA, dstA, ws);
  k_l1_post<<<4000, 256, 0, stream>>>(aE0, aT0, aE1, aT1, ws);
  k_relW<<<100, 256, 0, stream>>>(Rel, W, ws, out);
  k_l2_proj<<<2218, 256, 0, stream>>>(aEo, aTo, ws);
  k_l2_edge<<<1954, 256, 0, stream>>>(srcA, dstA, etyp, ws);
  k_l2_post<<<2000, 256, 0, stream>>>(ws, out);
}

// Round 3
// 560.464 us; speedup vs baseline: 4.8856x; 4.8856x over previous
//
#include <hip/hip_runtime.h>

#define ALPHA 0.2f
#define NT 1000
#define NRELC 200
#define NE 500000
#define N_ENT 100000

// ---------------- int workspace layout (int offsets) ----------------
static constexpr size_t I_STARTS_SRC = 0;        // 1001
static constexpr size_t I_STARTS_DST = 1001;     // 1001
static constexpr size_t I_CUR_SRC    = 2002;     // 1000 (counts, then cursors)
static constexpr size_t I_CUR_DST    = 3002;     // 1000
static constexpr size_t I_PERM_SRC   = 4002;     // 500000
static constexpr size_t I_PERM_DST   = 504002;   // 500000
static constexpr size_t I_OR_SRC     = 1004002;  // 500000 int2 (oth, rel)
static constexpr size_t I_OR_DST     = 2004002;  // 500000 int2

// ---------------- float workspace layout (float offsets) ----------------
static constexpr size_t F_U1 = 3004004;              // 4 combos x 3 parts x 64
static constexpr size_t F_U2 = F_U1 + 768;           // 2 combos x 3 parts x 128
static constexpr size_t F_L1 = F_U2 + 768;           // 4 combos x 130000
//   per-combo: P1 @0 (1000x64), P2 @64000 (1000x64), C1 @128000 (1000), C2 @129000 (1000)
static constexpr size_t F_X1 = F_L1 + 4*130000;      // 1000x128
static constexpr size_t F_X2 = F_X1 + 128000;        // 1000x128
static constexpr size_t F_OR = F_X2 + 128000;        // 200x128
static constexpr size_t F_L2 = F_OR + 25600;         // 2 combos x 283800
//   per-combo: Q1 @0 (1000x128), Q2 @128000, R3 @256000 (200x128),
//              C1 @281600 (1000), C2 @282600 (1000), C3 @283600 (200)
static constexpr size_t S2F = 283800;
static constexpr size_t WS_FLOATS = F_L2 + 2*S2F;    // ~4.37M floats = 17.5MB

// ---------------- output layout (floats) ----------------
static constexpr size_t OUT_O2  = 12800000;   // 100000*128
static constexpr size_t OUT_REL = 12928000;   // + 200*128

__device__ __forceinline__ float eluf(float x) { return x > 0.f ? x : expm1f(x); }
__device__ __forceinline__ float scoref(float slin) {
  return expf(slin > 0.f ? -slin : -ALPHA * slin);
}

// ================= sort: histogram -> scan -> scatter =================
__global__ void k_hist(const int* __restrict__ src, const int* __restrict__ dst,
                       int* __restrict__ ip) {
  int j = blockIdx.x * blockDim.x + threadIdx.x;
  if (j >= NE) return;
  atomicAdd(ip + I_CUR_SRC + src[j], 1);
  atomicAdd(ip + I_CUR_DST + dst[j], 1);
}

__global__ void k_scan(int* __restrict__ ip) {
  __shared__ int buf[1024];
  int t = threadIdx.x;
  for (int which = 0; which < 2; ++which) {
    int* cnt = ip + (which ? I_CUR_DST : I_CUR_SRC);
    int* st  = ip + (which ? I_STARTS_DST : I_STARTS_SRC);
    int v = (t < NT) ? cnt[t] : 0;
    buf[t] = v;
    __syncthreads();
    for (int off = 1; off < 1024; off <<= 1) {
      int x = (t >= off) ? buf[t - off] : 0;
      __syncthreads();
      buf[t] += x;
      __syncthreads();
    }
    if (t < NT) {
      int excl = buf[t] - v;
      st[t] = excl;
      cnt[t] = excl;          // cursor init
    }
    if (t == NT - 1) st[NT] = buf[t];  // total = NE
    __syncthreads();
  }
}

__global__ void k_scatter(const int* __restrict__ src, const int* __restrict__ dst,
                          const int* __restrict__ et, int* __restrict__ ip) {
  int j = blockIdx.x * blockDim.x + threadIdx.x;
  if (j >= NE) return;
  int s = src[j], d = dst[j], r = et[j];
  int p1 = atomicAdd(ip + I_CUR_SRC + s, 1);
  ip[I_PERM_SRC + p1] = j;
  reinterpret_cast<int2*>(ip + I_OR_SRC)[p1] = make_int2(d, r);
  int p2 = atomicAdd(ip + I_CUR_DST + d, 1);
  ip[I_PERM_DST + p2] = j;
  reinterpret_cast<int2*>(ip + I_OR_DST)[p2] = make_int2(s, r);
}

// ================= score-factorization u-vectors =================
__global__ void k_prep_u(const float* aE0, const float* vE0, const float* aT0, const float* vT0,
                         const float* aE1, const float* vE1, const float* aT1, const float* vT1,
                         const float* aEo, const float* vEo, const float* aTo, const float* vTo,
                         float* ws) {
  int t = blockIdx.x * blockDim.x + threadIdx.x;
  if (t < 768) {
    int c = t / 192, rem = t - c*192;
    int p = rem >> 6, k = rem & 63;
    const float* a = (c==0)?aE0:(c==1)?aT0:(c==2)?aE1:aT1;
    const float* v = (c==0)?vE0:(c==1)?vT0:(c==2)?vE1:vT1;
    float s = 0.f;
    for (int o = 0; o < 64; ++o) s += a[o*192 + p*64 + k] * v[o];
    ws[F_U1 + (size_t)(c*3+p)*64 + k] = s;
  } else if (t < 1536) {
    int tt = t - 768;
    int c = tt / 384, rem = tt - c*384;
    int p = rem >> 7, k = rem & 127;
    const float* a = c ? aTo : aEo;
    const float* v = c ? vTo : vEo;
    float s = 0.f;
    for (int o = 0; o < 128; ++o) s += a[o*384 + p*128 + k] * v[o];
    ws[F_U2 + (size_t)(c*3+p)*128 + k] = s;
  }
}

// ================= layer-1 projections P1,P2,C1,C2 =================
__global__ void k_l1_proj(const float* Ent, const float* Typ,
                          const float* aE0, const float* aT0,
                          const float* aE1, const float* aT1,
                          float* ws) {
  int stride = gridDim.x * blockDim.x;
  for (int t = blockIdx.x * blockDim.x + threadIdx.x; t < 4*130000; t += stride) {
    int c = t / 130000, rem = t - c*130000;
    const float* a = (c==0)?aE0:(c==1)?aT0:(c==2)?aE1:aT1;
    float* base = ws + F_L1 + (size_t)c * 130000;
    if (rem < 64000) {
      int i = rem >> 6, o = rem & 63;
      const float* x = Ent + (size_t)i*64;
      const float* ar = a + o*192;
      float s = 0.f;
      #pragma unroll
      for (int k = 0; k < 64; ++k) s += x[k]*ar[k];
      base[rem] = s;
    } else if (rem < 128000) {
      int rr = rem - 64000; int i = rr >> 6, o = rr & 63;
      const float* x = Typ + (size_t)i*64;
      const float* ar = a + o*192 + 64;
      float s = 0.f;
      #pragma unroll
      for (int k = 0; k < 64; ++k) s += x[k]*ar[k];
      base[64000 + rr] = s;
    } else if (rem < 129000) {
      int i = rem - 128000;
      const float* x = Ent + (size_t)i*64;
      const float* u = ws + F_U1 + (size_t)(c*3)*64;
      float s = 0.f;
      #pragma unroll
      for (int k = 0; k < 64; ++k) s += x[k]*u[k];
      base[128000 + i] = s;
    } else {
      int i = rem - 129000;
      const float* x = Typ + (size_t)i*64;
      const float* u = ws + F_U1 + (size_t)(c*3+1)*64;
      float s = 0.f;
      #pragma unroll
      for (int k = 0; k < 64; ++k) s += x[k]*u[k];
      base[129000 + i] = s;
    }
  }
}

// ================= layer-1 fused per-segment pass =================
// grid 2000: blocks [0,1000) = side 0 (seg=src, combos 0,2),
//            blocks [1000,2000) = side 1 (seg=dst, combos 1,3)
__global__ __launch_bounds__(256) void k_l1_seg(const float* __restrict__ Eemb,
                                                const float* aE0, const float* aT0,
                                                const float* aE1, const float* aT1,
                                                const int* __restrict__ ip,
                                                float* __restrict__ ws) {
  __shared__ float Tl[2][NT];
  __shared__ float cOthL[2][NT];
  __shared__ float accR[2][16][64];
  __shared__ float accE[2][64];
  __shared__ float red[256];
  __shared__ float denl[2];

  int side = blockIdx.x >= NT;
  int g = blockIdx.x - side * NT;
  int t = threadIdx.x;
  int sub = t & 15, slot = t >> 4;
  int c0 = side, c1 = side + 2;

  // zero + preload
  size_t othOff = side ? 128000 : 129000;   // C1 : C2
  size_t ownOff = side ? 129000 : 128000;
  for (int i = t; i < NT; i += 256) {
    Tl[0][i] = 0.f; Tl[1][i] = 0.f;
    cOthL[0][i] = ws[F_L1 + (size_t)c0*130000 + othOff + i];
    cOthL[1][i] = ws[F_L1 + (size_t)c1*130000 + othOff + i];
  }
  if (t < 2) denl[t] = 0.f;
  float ownA = ws[F_L1 + (size_t)c0*130000 + ownOff + g];
  float ownB = ws[F_L1 + (size_t)c1*130000 + ownOff + g];
  float4 w3A = reinterpret_cast<const float4*>(ws + F_U1 + (size_t)(c0*3+2)*64)[sub];
  float4 w3B = reinterpret_cast<const float4*>(ws + F_U1 + (size_t)(c1*3+2)*64)[sub];
  __syncthreads();

  int start = ip[(side ? I_STARTS_DST : I_STARTS_SRC) + g];
  int end   = ip[(side ? I_STARTS_DST : I_STARTS_SRC) + g + 1];
  const int*  perm = ip + (side ? I_PERM_DST : I_PERM_SRC);
  const int2* orl  = reinterpret_cast<const int2*>(ip + (side ? I_OR_DST : I_OR_SRC));

  float4 acc0 = make_float4(0.f,0.f,0.f,0.f);
  float4 acc1 = make_float4(0.f,0.f,0.f,0.f);
  float d0 = 0.f, d1 = 0.f;

  for (int p = start + slot; p < end; p += 16) {
    int j = perm[p];
    int2 o2 = orl[p];
    float4 ev = reinterpret_cast<const float4*>(Eemb)[(size_t)j*16 + sub];
    float rA = ev.x*w3A.x + ev.y*w3A.y + ev.z*w3A.z + ev.w*w3A.w;
    float rB = ev.x*w3B.x + ev.y*w3B.y + ev.z*w3B.z + ev.w*w3B.w;
    rA += __shfl_xor(rA, 1, 16); rB += __shfl_xor(rB, 1, 16);
    rA += __shfl_xor(rA, 2, 16); rB += __shfl_xor(rB, 2, 16);
    rA += __shfl_xor(rA, 4, 16); rB += __shfl_xor(rB, 4, 16);
    rA += __shfl_xor(rA, 8, 16); rB += __shfl_xor(rB, 8, 16);
    float sA = scoref(ownA + cOthL[0][o2.x] + rA);
    float sB = scoref(ownB + cOthL[1][o2.x] + rB);
    acc0.x += sA*ev.x; acc0.y += sA*ev.y; acc0.z += sA*ev.z; acc0.w += sA*ev.w;
    acc1.x += sB*ev.x; acc1.y += sB*ev.y; acc1.z += sB*ev.z; acc1.w += sB*ev.w;
    if (sub == 0) {
      atomicAdd(&Tl[0][o2.x], sA);
      atomicAdd(&Tl[1][o2.x], sB);
      d0 += sA; d1 += sB;
    }
  }
  *reinterpret_cast<float4*>(&accR[0][slot][sub*4]) = acc0;
  *reinterpret_cast<float4*>(&accR[1][slot][sub*4]) = acc1;
  if (sub == 0) { atomicAdd(&denl[0], d0); atomicAdd(&denl[1], d1); }
  __syncthreads();
  if (t < 128) {
    int ci = t >> 6, o = t & 63;
    float s = 0.f;
    #pragma unroll
    for (int sl = 0; sl < 16; ++sl) s += accR[ci][sl][o];
    accE[ci][o] = s;
  }
  __syncthreads();

  // fused post: num = den*Pown + Tl@Poth + accE@a3^T ; write x
  int o = t & 63, part = t >> 6;
  size_t othPOff = side ? 0 : 64000;   // P1 : P2
  size_t ownPOff = side ? 64000 : 0;
  #pragma unroll
  for (int ci = 0; ci < 2; ++ci) {
    int c = side + 2*ci;
    const float* Pc = ws + F_L1 + (size_t)c * 130000;
    const float* Poth = Pc + othPOff;
    float sum = 0.f;
    for (int dd = part*250; dd < part*250 + 250; ++dd)
      sum += Tl[ci][dd] * Poth[(size_t)dd*64 + o];
    red[t] = sum;
    __syncthreads();
    if (part == 0) {
      sum = red[o] + red[64+o] + red[128+o] + red[192+o];
      const float* a = (c==0)?aE0:(c==1)?aT0:(c==2)?aE1:aT1;
      const float* a3 = a + o*192 + 128;
      float acc = 0.f;
      #pragma unroll
      for (int k = 0; k < 64; ++k) acc += accE[ci][k]*a3[k];
      float den = denl[ci];
      float own = Pc[ownPOff + (size_t)g*64 + o];
      float num = sum + acc + den*own;
      float h = num / (den == 0.f ? 1.f : den);
      float* dst = ws + (side ? F_X2 : F_X1);
      dst[(size_t)g*128 + ci*64 + o] = eluf(h);
    }
    __syncthreads();
  }
}

// ================= out_rel = Rel @ W =================
__global__ void k_relW(const float* Rel, const float* W, float* ws, float* dout) {
  int t = blockIdx.x * blockDim.x + threadIdx.x;
  if (t >= NRELC*128) return;
  int r = t >> 7, o = t & 127;
  const float* x = Rel + (size_t)r*64;
  float s = 0.f;
  #pragma unroll
  for (int k = 0; k < 64; ++k) s += x[k] * W[(size_t)k*128 + o];
  ws[F_OR + t] = s;
  dout[OUT_REL + t] = s;
}

// ================= layer-2 projections =================
__global__ void k_l2_proj(const float* aEo, const float* aTo, float* ws) {
  int stride = gridDim.x * blockDim.x;
  const float* x1 = ws + F_X1;
  const float* x2 = ws + F_X2;
  const float* orel = ws + F_OR;
  for (int t = blockIdx.x * blockDim.x + threadIdx.x; t < 2*283800; t += stride) {
    int c = t / 283800, rem = t - c*283800;
    const float* a = c ? aTo : aEo;
    float* base = ws + F_L2 + (size_t)c * S2F;
    if (rem < 128000) {
      int i = rem >> 7, o = rem & 127;
      const float* x = x1 + (size_t)i*128;
      const float* ar = a + (size_t)o*384;
      float s = 0.f;
      #pragma unroll
      for (int k = 0; k < 128; ++k) s += x[k]*ar[k];
      base[rem] = s;
    } else if (rem < 256000) {
      int rr = rem - 128000; int i = rr >> 7, o = rr & 127;
      const float* x = x2 + (size_t)i*128;
      const float* ar = a + (size_t)o*384 + 128;
      float s = 0.f;
      #pragma unroll
      for (int k = 0; k < 128; ++k) s += x[k]*ar[k];
      base[128000 + rr] = s;
    } else if (rem < 281600) {
      int rr = rem - 256000; int r = rr >> 7, o = rr & 127;
      const float* x = orel + (size_t)r*128;
      const float* ar = a + (size_t)o*384 + 256;
      float s = 0.f;
      #pragma unroll
      for (int k = 0; k < 128; ++k) s += x[k]*ar[k];
      base[256000 + rr] = s;
    } else if (rem < 282600) {
      int i = rem - 281600;
      const float* u = ws + F_U2 + (size_t)(c*3)*128;
      const float* x = x1 + (size_t)i*128;
      float s = 0.f;
      for (int k = 0; k < 128; ++k) s += x[k]*u[k];
      base[281600 + i] = s;
    } else if (rem < 283600) {
      int i = rem - 282600;
      const float* u = ws + F_U2 + (size_t)(c*3+1)*128;
      const float* x = x2 + (size_t)i*128;
      float s = 0.f;
      for (int k = 0; k < 128; ++k) s += x[k]*u[k];
      base[282600 + i] = s;
    } else {
      int r = rem - 283600;
      const float* u = ws + F_U2 + (size_t)(c*3+2)*128;
      const float* x = orel + (size_t)r*128;
      float s = 0.f;
      for (int k = 0; k < 128; ++k) s += x[k]*u[k];
      base[283600 + r] = s;
    }
  }
}

// ================= layer-2 fused per-segment pass =================
// grid 2000: blocks [0,1000) = combo 0 (seg=src), [1000,2000) = combo 1 (seg=dst)
__global__ __launch_bounds__(256) void k_l2_seg(const int* __restrict__ ip,
                                                float* __restrict__ ws,
                                                float* __restrict__ dout) {
  __shared__ float Tl[NT];
  __shared__ float Ul[NRELC];
  __shared__ float cOthL[NT];
  __shared__ float cRelL[NRELC];
  __shared__ float red[256];
  __shared__ float denl;

  int c = blockIdx.x >= NT;
  int g = blockIdx.x - c * NT;
  int t = threadIdx.x;
  float* base = ws + F_L2 + (size_t)c * S2F;

  size_t othOff = c ? 281600 : 282600;   // C1 : C2
  size_t ownOff = c ? 282600 : 281600;
  for (int i = t; i < NT; i += 256) { Tl[i] = 0.f; cOthL[i] = base[othOff + i]; }
  for (int i = t; i < NRELC; i += 256) { Ul[i] = 0.f; cRelL[i] = base[283600 + i]; }
  if (t == 0) denl = 0.f;
  float own = base[ownOff + g];
  __syncthreads();

  int start = ip[(c ? I_STARTS_DST : I_STARTS_SRC) + g];
  int end   = ip[(c ? I_STARTS_DST : I_STARTS_SRC) + g + 1];
  const int2* orl = reinterpret_cast<const int2*>(ip + (c ? I_OR_DST : I_OR_SRC));

  float dpart = 0.f;
  for (int p = start + t; p < end; p += 256) {
    int2 o2 = orl[p];
    float sv = scoref(own + cOthL[o2.x] + cRelL[o2.y]);
    atomicAdd(&Tl[o2.x], sv);
    atomicAdd(&Ul[o2.y], sv);
    dpart += sv;
  }
  atomicAdd(&denl, dpart);
  __syncthreads();

  int o = t & 127, part = t >> 7;
  const float* Qoth = base + (c ? 0 : 128000);   // Q1 : Q2
  const float* R3 = base + 256000;
  float sum = 0.f;
  for (int dd = part*500; dd < part*500 + 500; ++dd)
    sum += Tl[dd] * Qoth[(size_t)dd*128 + o];
  for (int rr = part*100; rr < part*100 + 100; ++rr)
    sum += Ul[rr] * R3[(size_t)rr*128 + o];
  red[t] = sum;
  __syncthreads();
  if (part == 0) {
    sum = red[o] + red[128+o];
    float den = denl;
    float ownQ = base[(c ? 128000 : 0) + (size_t)g*128 + o];
    float num = sum + den*ownQ;
    float h = num / (den == 0.f ? 1.f : den);
    size_t off = c ? (OUT_O2 + (size_t)g*128 + o) : ((size_t)g*128 + o);
    dout[off] = eluf(h);
  }
}

extern "C" void kernel_launch(void* const* d_in, const int* in_sizes, int n_in,
                              void* d_out, int out_size, void* d_ws, size_t ws_size,
                              hipStream_t stream) {
  (void)in_sizes; (void)n_in;
  const float* Ent = (const float*)d_in[0];
  const float* Typ = (const float*)d_in[1];
  const float* Rel = (const float*)d_in[2];
  const int*   edge = (const int*)d_in[3];
  const int*   etyp = (const int*)d_in[4];
  const float* Eemb = (const float*)d_in[5];
  const float* aE0 = (const float*)d_in[6];
  const float* vE0 = (const float*)d_in[7];
  const float* aT0 = (const float*)d_in[8];
  const float* vT0 = (const float*)d_in[9];
  const float* aE1 = (const float*)d_in[10];
  const float* vE1 = (const float*)d_in[11];
  const float* aT1 = (const float*)d_in[12];
  const float* vT1 = (const float*)d_in[13];
  const float* aEo = (const float*)d_in[14];
  const float* vEo = (const float*)d_in[15];
  const float* aTo = (const float*)d_in[16];
  const float* vTo = (const float*)d_in[17];
  const float* W   = (const float*)d_in[18];
  float* ws  = (float*)d_ws;
  int*   ip  = (int*)d_ws;
  float* out = (float*)d_out;
  const int* srcA = edge;
  const int* dstA = edge + NE;

  if (ws_size < WS_FLOATS * sizeof(float)) return;

  // zero output tail (o1 rows >= 1000 stay exactly elu(0)=0) and sort counters
  hipMemsetAsync(d_out, 0, (size_t)out_size * sizeof(float), stream);
  hipMemsetAsync(d_ws, 0, 4002 * sizeof(int), stream);

  k_hist   <<<1954, 256, 0, stream>>>(srcA, dstA, ip);
  k_scan   <<<1, 1024, 0, stream>>>(ip);
  k_scatter<<<1954, 256, 0, stream>>>(srcA, dstA, etyp, ip);
  k_prep_u <<<6, 256, 0, stream>>>(aE0,vE0,aT0,vT0,aE1,vE1,aT1,vT1,aEo,vEo,aTo,vTo,ws);
  k_l1_proj<<<2048, 256, 0, stream>>>(Ent, Typ, aE0, aT0, aE1, aT1, ws);
  k_l1_seg <<<2000, 256, 0, stream>>>(Eemb, aE0, aT0, aE1, aT1, ip, ws);
  k_relW   <<<100, 256, 0, stream>>>(Rel, W, ws, out);
  k_l2_proj<<<2218, 256, 0, stream>>>(aEo, aTo, ws);
  k_l2_seg <<<2000, 256, 0, stream>>>(ip, ws, out);
}

// Round 5
// 321.234 us; speedup vs baseline: 8.5240x; 1.7447x over previous
//
#include <hip/hip_runtime.h>

#define ALPHA 0.2f
#define NT 1000
#define NRELC 200
#define NE 500000
#define N_ENT 100000
#define CH 4096
#define G 123            // ceil(NE/CH)

// ---------------- int workspace layout (int offsets) ----------------
static constexpr size_t I_STARTS_SRC = 0;        // 1001
static constexpr size_t I_STARTS_DST = 1001;     // 1001
static constexpr size_t I_HIST2      = 2002;     // 2*G*NT = 246000  [side][blk][bin]
static constexpr size_t I_BASE2      = 248002;   // 246000           [side][blk][bin]
static constexpr size_t I_AB_SRC     = 494002;   // 1000000 (500000 int2: j, oth|rel<<16)
static constexpr size_t I_AB_DST     = 1494002;  // 1000000

// ---------------- float workspace layout (float offsets) ----------------
static constexpr size_t F_U1 = 2494004;              // 4 combos x 3 parts x 64
static constexpr size_t F_U2 = F_U1 + 768;           // 2 combos x 3 parts x 128
static constexpr size_t F_L1 = F_U2 + 768;           // 4 combos x 130000
//   per-combo: P1 @0 (1000x64), P2 @64000 (1000x64), C1 @128000 (1000), C2 @129000 (1000)
static constexpr size_t F_X1 = F_L1 + 4*130000;      // 1000x128
static constexpr size_t F_X2 = F_X1 + 128000;        // 1000x128
static constexpr size_t F_OR = F_X2 + 128000;        // 200x128
static constexpr size_t F_L2 = F_OR + 25600;         // 2 combos x 283800
//   per-combo: Q1 @0 (1000x128), Q2 @128000, R3 @256000 (200x128),
//              C1 @281600 (1000), C2 @282600 (1000), C3 @283600 (200)
static constexpr size_t S2F = 283800;
static constexpr size_t WS_FLOATS = F_L2 + 2*S2F;    // ~3.86M floats = 15.5MB

// ---------------- output layout (floats) ----------------
static constexpr size_t OUT_O2  = 12800000;   // 100000*128
static constexpr size_t OUT_REL = 12928000;   // + 200*128

__device__ __forceinline__ float eluf(float x) { return x > 0.f ? x : expm1f(x); }
__device__ __forceinline__ float scoref(float slin) {
  return expf(slin > 0.f ? -slin : -ALPHA * slin);
}

// ================= sort phase 1: per-chunk histograms (no atomics to global) ===
__global__ __launch_bounds__(256) void k_hist2(const int* __restrict__ src,
                                               const int* __restrict__ dst,
                                               int* __restrict__ ip) {
  __shared__ int h[NT];
  int bid = blockIdx.x;
  int side = bid >= G;
  int blk = bid - side * G;
  const int* keys = side ? dst : src;
  int j0 = blk * CH;
  int n = min(CH, NE - j0);
  for (int i = threadIdx.x; i < NT; i += 256) h[i] = 0;
  __syncthreads();
  for (int k = threadIdx.x; k < n; k += 256) atomicAdd(&h[keys[j0 + k]], 1);
  __syncthreads();
  int* row = ip + I_HIST2 + (size_t)(side * G + blk) * NT;
  for (int b = threadIdx.x; b < NT; b += 256) row[b] = h[b];
}

// ================= sort phase 2: global starts + per-(blk,bin) bases ==========
__global__ void k_scan2(int* __restrict__ ip) {
  __shared__ int buf[1024];
  int t = threadIdx.x;   // 1024 threads
  for (int side = 0; side < 2; ++side) {
    int cnt = 0;
    if (t < NT) {
      for (int blk = 0; blk < G; ++blk)
        cnt += ip[I_HIST2 + (size_t)(side * G + blk) * NT + t];
    }
    buf[t] = (t < NT) ? cnt : 0;
    __syncthreads();
    for (int off = 1; off < 1024; off <<= 1) {
      int x = (t >= off) ? buf[t - off] : 0;
      __syncthreads();
      buf[t] += x;
      __syncthreads();
    }
    int* st = ip + (side ? I_STARTS_DST : I_STARTS_SRC);
    if (t < NT) {
      int excl = buf[t] - cnt;
      st[t] = excl;
      int run = excl;
      for (int blk = 0; blk < G; ++blk) {
        size_t idx = I_HIST2 + (size_t)(side * G + blk) * NT + t;
        int c = ip[idx];
        ip[idx + (I_BASE2 - I_HIST2)] = run;
        run += c;
      }
    }
    if (t == NT - 1) st[NT] = buf[t];
    __syncthreads();
  }
}

// ================= sort phase 3: LDS-binned scatter, run-coalesced writes =====
__global__ __launch_bounds__(256) void k_binscat(const int* __restrict__ src,
                                                 const int* __restrict__ dst,
                                                 const int* __restrict__ et,
                                                 int* __restrict__ ip) {
  __shared__ int2 bufs[CH];      // 32KB staging
  __shared__ int loff[1024];
  __shared__ int lcur[1024];
  __shared__ int gbase[1024];
  __shared__ int psum[256];
  int bid = blockIdx.x;
  int side = bid >= G;
  int blk = bid - side * G;
  const int* keys = side ? dst : src;
  const int* oths = side ? src : dst;
  int j0 = blk * CH;
  int n = min(CH, NE - j0);
  int t = threadIdx.x;

  for (int i = t; i < 1024; i += 256) lcur[i] = 0;
  __syncthreads();
  for (int k = t; k < n; k += 256) atomicAdd(&lcur[keys[j0 + k]], 1);
  __syncthreads();
  // local exclusive scan over 1024 bins (4 bins/thread)
  int c0 = lcur[4*t], c1 = lcur[4*t+1], c2 = lcur[4*t+2], c3 = lcur[4*t+3];
  int s = c0 + c1 + c2 + c3;
  psum[t] = s;
  __syncthreads();
  for (int off = 1; off < 256; off <<= 1) {
    int x = (t >= off) ? psum[t - off] : 0;
    __syncthreads();
    psum[t] += x;
    __syncthreads();
  }
  int base = psum[t] - s;
  loff[4*t]   = base;
  loff[4*t+1] = base + c0;
  loff[4*t+2] = base + c0 + c1;
  loff[4*t+3] = base + c0 + c1 + c2;
  lcur[4*t]   = loff[4*t];
  lcur[4*t+1] = loff[4*t+1];
  lcur[4*t+2] = loff[4*t+2];
  lcur[4*t+3] = loff[4*t+3];
  const int* brow = ip + I_BASE2 + (size_t)(side * G + blk) * NT;
  for (int b = t; b < NT; b += 256) gbase[b] = brow[b];
  __syncthreads();
  // scatter into LDS (bin packed into high bits of j)
  for (int k = t; k < n; k += 256) {
    int j = j0 + k;
    int b = keys[j];
    int pos = atomicAdd(&lcur[b], 1);
    bufs[pos] = make_int2(j | (b << 19), oths[j] | (et[j] << 16));
  }
  __syncthreads();
  // stream out: consecutive k -> same-bin runs -> coalesced global writes
  int2* out = reinterpret_cast<int2*>(ip + (side ? I_AB_DST : I_AB_SRC));
  for (int k = t; k < n; k += 256) {
    int2 q = bufs[k];
    int b = q.x >> 19;
    int posg = gbase[b] + (k - loff[b]);
    out[posg] = make_int2(q.x & 0x7FFFF, q.y);
  }
}

// ================= score-factorization u-vectors =================
__global__ void k_prep_u(const float* aE0, const float* vE0, const float* aT0, const float* vT0,
                         const float* aE1, const float* vE1, const float* aT1, const float* vT1,
                         const float* aEo, const float* vEo, const float* aTo, const float* vTo,
                         float* ws) {
  int t = blockIdx.x * blockDim.x + threadIdx.x;
  if (t < 768) {
    int c = t / 192, rem = t - c*192;
    int p = rem >> 6, k = rem & 63;
    const float* a = (c==0)?aE0:(c==1)?aT0:(c==2)?aE1:aT1;
    const float* v = (c==0)?vE0:(c==1)?vT0:(c==2)?vE1:vT1;
    float s = 0.f;
    for (int o = 0; o < 64; ++o) s += a[o*192 + p*64 + k] * v[o];
    ws[F_U1 + (size_t)(c*3+p)*64 + k] = s;
  } else if (t < 1536) {
    int tt = t - 768;
    int c = tt / 384, rem = tt - c*384;
    int p = rem >> 7, k = rem & 127;
    const float* a = c ? aTo : aEo;
    const float* v = c ? vTo : vEo;
    float s = 0.f;
    for (int o = 0; o < 128; ++o) s += a[o*384 + p*128 + k] * v[o];
    ws[F_U2 + (size_t)(c*3+p)*128 + k] = s;
  }
}

// ================= layer-1 projections P1,P2,C1,C2 =================
__global__ void k_l1_proj(const float* Ent, const float* Typ,
                          const float* aE0, const float* aT0,
                          const float* aE1, const float* aT1,
                          float* ws) {
  int stride = gridDim.x * blockDim.x;
  for (int t = blockIdx.x * blockDim.x + threadIdx.x; t < 4*130000; t += stride) {
    int c = t / 130000, rem = t - c*130000;
    const float* a = (c==0)?aE0:(c==1)?aT0:(c==2)?aE1:aT1;
    float* base = ws + F_L1 + (size_t)c * 130000;
    if (rem < 64000) {
      int i = rem >> 6, o = rem & 63;
      const float* x = Ent + (size_t)i*64;
      const float* ar = a + o*192;
      float s = 0.f;
      #pragma unroll
      for (int k = 0; k < 64; ++k) s += x[k]*ar[k];
      base[rem] = s;
    } else if (rem < 128000) {
      int rr = rem - 64000; int i = rr >> 6, o = rr & 63;
      const float* x = Typ + (size_t)i*64;
      const float* ar = a + o*192 + 64;
      float s = 0.f;
      #pragma unroll
      for (int k = 0; k < 64; ++k) s += x[k]*ar[k];
      base[64000 + rr] = s;
    } else if (rem < 129000) {
      int i = rem - 128000;
      const float* x = Ent + (size_t)i*64;
      const float* u = ws + F_U1 + (size_t)(c*3)*64;
      float s = 0.f;
      #pragma unroll
      for (int k = 0; k < 64; ++k) s += x[k]*u[k];
      base[128000 + i] = s;
    } else {
      int i = rem - 129000;
      const float* x = Typ + (size_t)i*64;
      const float* u = ws + F_U1 + (size_t)(c*3+1)*64;
      float s = 0.f;
      #pragma unroll
      for (int k = 0; k < 64; ++k) s += x[k]*u[k];
      base[129000 + i] = s;
    }
  }
}

// ================= layer-1 fused per-segment pass =================
// grid 2000: blocks [0,1000) = side 0 (seg=src, combos 0,2),
//            blocks [1000,2000) = side 1 (seg=dst, combos 1,3)
__global__ __launch_bounds__(256) void k_l1_seg(const float* __restrict__ Eemb,
                                                const float* aE0, const float* aT0,
                                                const float* aE1, const float* aT1,
                                                const int* __restrict__ ip,
                                                float* __restrict__ ws) {
  __shared__ float Tl[2][NT];
  __shared__ float cOthL[2][NT];
  __shared__ float accR[2][16][64];
  __shared__ float accE[2][64];
  __shared__ float red[256];
  __shared__ float denl[2];

  int side = blockIdx.x >= NT;
  int g = blockIdx.x - side * NT;
  int t = threadIdx.x;
  int sub = t & 15, slot = t >> 4;
  int c0 = side, c1 = side + 2;

  size_t othOff = side ? 128000 : 129000;   // C1 : C2
  size_t ownOff = side ? 129000 : 128000;
  for (int i = t; i < NT; i += 256) {
    Tl[0][i] = 0.f; Tl[1][i] = 0.f;
    cOthL[0][i] = ws[F_L1 + (size_t)c0*130000 + othOff + i];
    cOthL[1][i] = ws[F_L1 + (size_t)c1*130000 + othOff + i];
  }
  if (t < 2) denl[t] = 0.f;
  float ownA = ws[F_L1 + (size_t)c0*130000 + ownOff + g];
  float ownB = ws[F_L1 + (size_t)c1*130000 + ownOff + g];
  float4 w3A = reinterpret_cast<const float4*>(ws + F_U1 + (size_t)(c0*3+2)*64)[sub];
  float4 w3B = reinterpret_cast<const float4*>(ws + F_U1 + (size_t)(c1*3+2)*64)[sub];
  __syncthreads();

  int start = ip[(side ? I_STARTS_DST : I_STARTS_SRC) + g];
  int end   = ip[(side ? I_STARTS_DST : I_STARTS_SRC) + g + 1];
  const int2* ab = reinterpret_cast<const int2*>(ip + (side ? I_AB_DST : I_AB_SRC));

  float4 acc0 = make_float4(0.f,0.f,0.f,0.f);
  float4 acc1 = make_float4(0.f,0.f,0.f,0.f);
  float d0 = 0.f, d1 = 0.f;

  for (int p = start + slot; p < end; p += 16) {
    int2 q = ab[p];
    int j = q.x;
    int oth = q.y & 0xFFFF;
    float4 ev = reinterpret_cast<const float4*>(Eemb)[(size_t)j*16 + sub];
    float rA = ev.x*w3A.x + ev.y*w3A.y + ev.z*w3A.z + ev.w*w3A.w;
    float rB = ev.x*w3B.x + ev.y*w3B.y + ev.z*w3B.z + ev.w*w3B.w;
    rA += __shfl_xor(rA, 1, 16); rB += __shfl_xor(rB, 1, 16);
    rA += __shfl_xor(rA, 2, 16); rB += __shfl_xor(rB, 2, 16);
    rA += __shfl_xor(rA, 4, 16); rB += __shfl_xor(rB, 4, 16);
    rA += __shfl_xor(rA, 8, 16); rB += __shfl_xor(rB, 8, 16);
    float sA = scoref(ownA + cOthL[0][oth] + rA);
    float sB = scoref(ownB + cOthL[1][oth] + rB);
    acc0.x += sA*ev.x; acc0.y += sA*ev.y; acc0.z += sA*ev.z; acc0.w += sA*ev.w;
    acc1.x += sB*ev.x; acc1.y += sB*ev.y; acc1.z += sB*ev.z; acc1.w += sB*ev.w;
    if (sub == 0) {
      atomicAdd(&Tl[0][oth], sA);
      atomicAdd(&Tl[1][oth], sB);
      d0 += sA; d1 += sB;
    }
  }
  *reinterpret_cast<float4*>(&accR[0][slot][sub*4]) = acc0;
  *reinterpret_cast<float4*>(&accR[1][slot][sub*4]) = acc1;
  if (sub == 0) { atomicAdd(&denl[0], d0); atomicAdd(&denl[1], d1); }
  __syncthreads();
  if (t < 128) {
    int ci = t >> 6, o = t & 63;
    float s = 0.f;
    #pragma unroll
    for (int sl = 0; sl < 16; ++sl) s += accR[ci][sl][o];
    accE[ci][o] = s;
  }
  __syncthreads();

  // fused post: num = den*Pown + Tl@Poth + accE@a3^T ; write x
  int o = t & 63, part = t >> 6;
  size_t othPOff = side ? 0 : 64000;   // P1 : P2
  size_t ownPOff = side ? 64000 : 0;
  #pragma unroll
  for (int ci = 0; ci < 2; ++ci) {
    int c = side + 2*ci;
    const float* Pc = ws + F_L1 + (size_t)c * 130000;
    const float* Poth = Pc + othPOff;
    float sum = 0.f;
    for (int dd = part*250; dd < part*250 + 250; ++dd)
      sum += Tl[ci][dd] * Poth[(size_t)dd*64 + o];
    red[t] = sum;
    __syncthreads();
    if (part == 0) {
      sum = red[o] + red[64+o] + red[128+o] + red[192+o];
      const float* a = (c==0)?aE0:(c==1)?aT0:(c==2)?aE1:aT1;
      const float* a3 = a + o*192 + 128;
      float acc = 0.f;
      #pragma unroll
      for (int k = 0; k < 64; ++k) acc += accE[ci][k]*a3[k];
      float den = denl[ci];
      float own = Pc[ownPOff + (size_t)g*64 + o];
      float num = sum + acc + den*own;
      float h = num / (den == 0.f ? 1.f : den);
      float* dst = ws + (side ? F_X2 : F_X1);
      dst[(size_t)g*128 + ci*64 + o] = eluf(h);
    }
    __syncthreads();
  }
}

// ================= out_rel = Rel @ W =================
__global__ void k_relW(const float* Rel, const float* W, float* ws, float* dout) {
  int t = blockIdx.x * blockDim.x + threadIdx.x;
  if (t >= NRELC*128) return;
  int r = t >> 7, o = t & 127;
  const float* x = Rel + (size_t)r*64;
  float s = 0.f;
  #pragma unroll
  for (int k = 0; k < 64; ++k) s += x[k] * W[(size_t)k*128 + o];
  ws[F_OR + t] = s;
  dout[OUT_REL + t] = s;
}

// ================= layer-2 projections =================
__global__ void k_l2_proj(const float* aEo, const float* aTo, float* ws) {
  int stride = gridDim.x * blockDim.x;
  const float* x1 = ws + F_X1;
  const float* x2 = ws + F_X2;
  const float* orel = ws + F_OR;
  for (int t = blockIdx.x * blockDim.x + threadIdx.x; t < 2*283800; t += stride) {
    int c = t / 283800, rem = t - c*283800;
    const float* a = c ? aTo : aEo;
    float* base = ws + F_L2 + (size_t)c * S2F;
    if (rem < 128000) {
      int i = rem >> 7, o = rem & 127;
      const float* x = x1 + (size_t)i*128;
      const float* ar = a + (size_t)o*384;
      float s = 0.f;
      #pragma unroll
      for (int k = 0; k < 128; ++k) s += x[k]*ar[k];
      base[rem] = s;
    } else if (rem < 256000) {
      int rr = rem - 128000; int i = rr >> 7, o = rr & 127;
      const float* x = x2 + (size_t)i*128;
      const float* ar = a + (size_t)o*384 + 128;
      float s = 0.f;
      #pragma unroll
      for (int k = 0; k < 128; ++k) s += x[k]*ar[k];
      base[128000 + rr] = s;
    } else if (rem < 281600) {
      int rr = rem - 256000; int r = rr >> 7, o = rr & 127;
      const float* x = orel + (size_t)r*128;
      const float* ar = a + (size_t)o*384 + 256;
      float s = 0.f;
      #pragma unroll
      for (int k = 0; k < 128; ++k) s += x[k]*ar[k];
      base[256000 + rr] = s;
    } else if (rem < 282600) {
      int i = rem - 281600;
      const float* u = ws + F_U2 + (size_t)(c*3)*128;
      const float* x = x1 + (size_t)i*128;
      float s = 0.f;
      for (int k = 0; k < 128; ++k) s += x[k]*u[k];
      base[281600 + i] = s;
    } else if (rem < 283600) {
      int i = rem - 282600;
      const float* u = ws + F_U2 + (size_t)(c*3+1)*128;
      const float* x = x2 + (size_t)i*128;
      float s = 0.f;
      for (int k = 0; k < 128; ++k) s += x[k]*u[k];
      base[282600 + i] = s;
    } else {
      int r = rem - 283600;
      const float* u = ws + F_U2 + (size_t)(c*3+2)*128;
      const float* x = orel + (size_t)r*128;
      float s = 0.f;
      for (int k = 0; k < 128; ++k) s += x[k]*u[k];
      base[283600 + r] = s;
    }
  }
}

// ================= layer-2 fused per-segment pass =================
// grid 2000: blocks [0,1000) = combo 0 (seg=src), [1000,2000) = combo 1 (seg=dst)
__global__ __launch_bounds__(256) void k_l2_seg(const int* __restrict__ ip,
                                                float* __restrict__ ws,
                                                float* __restrict__ dout) {
  __shared__ float Tl[NT];
  __shared__ float Ul[NRELC];
  __shared__ float cOthL[NT];
  __shared__ float cRelL[NRELC];
  __shared__ float red[256];
  __shared__ float denl;

  int c = blockIdx.x >= NT;
  int g = blockIdx.x - c * NT;
  int t = threadIdx.x;
  float* base = ws + F_L2 + (size_t)c * S2F;

  size_t othOff = c ? 281600 : 282600;   // C1 : C2
  size_t ownOff = c ? 282600 : 281600;
  for (int i = t; i < NT; i += 256) { Tl[i] = 0.f; cOthL[i] = base[othOff + i]; }
  for (int i = t; i < NRELC; i += 256) { Ul[i] = 0.f; cRelL[i] = base[283600 + i]; }
  if (t == 0) denl = 0.f;
  float own = base[ownOff + g];
  __syncthreads();

  int start = ip[(c ? I_STARTS_DST : I_STARTS_SRC) + g];
  int end   = ip[(c ? I_STARTS_DST : I_STARTS_SRC) + g + 1];
  const int2* ab = reinterpret_cast<const int2*>(ip + (c ? I_AB_DST : I_AB_SRC));

  float dpart = 0.f;
  for (int p = start + t; p < end; p += 256) {
    int2 q = ab[p];
    int oth = q.y & 0xFFFF;
    int r = q.y >> 16;
    float sv = scoref(own + cOthL[oth] + cRelL[r]);
    atomicAdd(&Tl[oth], sv);
    atomicAdd(&Ul[r], sv);
    dpart += sv;
  }
  atomicAdd(&denl, dpart);
  __syncthreads();

  int o = t & 127, part = t >> 7;
  const float* Qoth = base + (c ? 0 : 128000);   // Q1 : Q2
  const float* R3 = base + 256000;
  float sum = 0.f;
  for (int dd = part*500; dd < part*500 + 500; ++dd)
    sum += Tl[dd] * Qoth[(size_t)dd*128 + o];
  for (int rr = part*100; rr < part*100 + 100; ++rr)
    sum += Ul[rr] * R3[(size_t)rr*128 + o];
  red[t] = sum;
  __syncthreads();
  if (part == 0) {
    sum = red[o] + red[128+o];
    float den = denl;
    float ownQ = base[(c ? 128000 : 0) + (size_t)g*128 + o];
    float num = sum + den*ownQ;
    float h = num / (den == 0.f ? 1.f : den);
    size_t off = c ? (OUT_O2 + (size_t)g*128 + o) : ((size_t)g*128 + o);
    dout[off] = eluf(h);
  }
}

extern "C" void kernel_launch(void* const* d_in, const int* in_sizes, int n_in,
                              void* d_out, int out_size, void* d_ws, size_t ws_size,
                              hipStream_t stream) {
  (void)in_sizes; (void)n_in;
  const float* Ent = (const float*)d_in[0];
  const float* Typ = (const float*)d_in[1];
  const float* Rel = (const float*)d_in[2];
  const int*   edge = (const int*)d_in[3];
  const int*   etyp = (const int*)d_in[4];
  const float* Eemb = (const float*)d_in[5];
  const float* aE0 = (const float*)d_in[6];
  const float* vE0 = (const float*)d_in[7];
  const float* aT0 = (const float*)d_in[8];
  const float* vT0 = (const float*)d_in[9];
  const float* aE1 = (const float*)d_in[10];
  const float* vE1 = (const float*)d_in[11];
  const float* aT1 = (const float*)d_in[12];
  const float* vT1 = (const float*)d_in[13];
  const float* aEo = (const float*)d_in[14];
  const float* vEo = (const float*)d_in[15];
  const float* aTo = (const float*)d_in[16];
  const float* vTo = (const float*)d_in[17];
  const float* W   = (const float*)d_in[18];
  float* ws  = (float*)d_ws;
  int*   ip  = (int*)d_ws;
  float* out = (float*)d_out;
  const int* srcA = edge;
  const int* dstA = edge + NE;

  if (ws_size < WS_FLOATS * sizeof(float)) return;

  // zero output (o1 rows >= 1000 stay exactly elu(0)=0); all ws arrays are
  // fully overwritten every call -> no ws memset needed (graph-replay safe)
  hipMemsetAsync(d_out, 0, (size_t)out_size * sizeof(float), stream);

  k_hist2  <<<2*G, 256, 0, stream>>>(srcA, dstA, ip);
  k_scan2  <<<1, 1024, 0, stream>>>(ip);
  k_binscat<<<2*G, 256, 0, stream>>>(srcA, dstA, etyp, ip);
  k_prep_u <<<6, 256, 0, stream>>>(aE0,vE0,aT0,vT0,aE1,vE1,aT1,vT1,aEo,vEo,aTo,vTo,ws);
  k_l1_proj<<<2048, 256, 0, stream>>>(Ent, Typ, aE0, aT0, aE1, aT1, ws);
  k_l1_seg <<<2000, 256, 0, stream>>>(Eemb, aE0, aT0, aE1, aT1, ip, ws);
  k_relW   <<<100, 256, 0, stream>>>(Rel, W, ws, out);
  k_l2_proj<<<2218, 256, 0, stream>>>(aEo, aTo, ws);
  k_l2_seg <<<2000, 256, 0, stream>>>(ip, ws, out);
}